// Round 9
// baseline (279.782 us; speedup 1.0000x reference)
//
#include <hip/hip_runtime.h>

#define NN 20000
#define NE 640000
#define NBUK 79  // ceil(20000/256) buckets of 256 nodes

// ---------------- bf16 helpers (RNE pack, branchless unpack) ----------------
__device__ __forceinline__ unsigned short f2b(float f) {
  unsigned int u = __float_as_uint(f);
  u += 0x7FFFu + ((u >> 16) & 1u);
  return (unsigned short)(u >> 16);
}
__device__ __forceinline__ float blo(unsigned int w) {  // low bf16 of word
  return __uint_as_float(w << 16);
}
__device__ __forceinline__ float bhi(unsigned int w) {  // high bf16 of word
  return __uint_as_float(w & 0xFFFF0000u);
}
__device__ __forceinline__ void bacc8(float* a, uint4 v) {
  a[0] += blo(v.x); a[1] += bhi(v.x);
  a[2] += blo(v.y); a[3] += bhi(v.y);
  a[4] += blo(v.z); a[5] += bhi(v.z);
  a[6] += blo(v.w); a[7] += bhi(v.w);
}
__device__ __forceinline__ void bget8(float* a, uint4 v) {
  a[0] = blo(v.x); a[1] = bhi(v.x);
  a[2] = blo(v.y); a[3] = bhi(v.y);
  a[4] = blo(v.z); a[5] = bhi(v.z);
  a[6] = blo(v.w); a[7] = bhi(v.w);
}
__device__ __forceinline__ unsigned int pk2(float lo, float hi) {
  return (unsigned int)f2b(lo) | ((unsigned int)f2b(hi) << 16);
}

// Self-probe: int64 edge data (values < 2^31) has every odd int32 word == 0.
__device__ __forceinline__ int probe_stride(const int* __restrict__ ei32) {
  int lane = threadIdx.x & 63;
  int v = ei32[2 * lane + 1];
  unsigned long long nz = __ballot(v != 0);
  return (nz == 0ull) ? 2 : 1;
}

__device__ __forceinline__ bool maskB(int var, int o2, int o1) {
  int s = o2 + o1;
  switch (var) {
    case 0: return (o2 >= 0) && (s >= 0);
    case 1: return s >= -1;
    case 3: return s <= 1;
    case 4: return (o2 <= 0) && (s <= 0);
    default: return true;
  }
}

// ============================ PHASE A1 =======================================
// blocks [0,151): weight setup; blocks [151,308): private-row histogram.
__global__ __launch_bounds__(256) void k_phaseA1(
    const int* __restrict__ ei, int* __restrict__ bhist,
    const float* __restrict__ Wc1, const float* __restrict__ Wc2,
    const float* __restrict__ Wc3, const float* __restrict__ bc1,
    const float* __restrict__ bc2, const float* __restrict__ bc3,
    const float* __restrict__ Wl1, const float* __restrict__ Wr1,
    const float* __restrict__ Wl2, const float* __restrict__ Wr2,
    const float* __restrict__ bl2,
    float* __restrict__ T729, float* __restrict__ beta5,
    float* __restrict__ Wt1, float* __restrict__ Wt2,
    float* __restrict__ Sbuf, float* __restrict__ c5,
    int* __restrict__ rowptr, int E, int N) {
  __shared__ float smem[6336];  // max branch: T729 (576+5184+576)
  int b = blockIdx.x, tid = threadIdx.x;
  if (b >= 151) {
    int* lb = (int*)smem;
    int st = probe_stride(ei);
    for (int i = tid; i < NBUK; i += 256) lb[i] = 0;
    __syncthreads();
    int u = b - 151;
    int e0 = u * 4096;
#pragma unroll
    for (int t = 0; t < 16; ++t) {
      int e = e0 + t * 256 + tid;
      if (e < E) atomicAdd(&lb[ei[(size_t)(E + e) * st] >> 8], 1);
    }
    __syncthreads();
    for (int i = tid; i < NBUK; i += 256) bhist[u * NBUK + i] = lb[i];
    return;
  }
  int s = b;
  if (s == 0) {
    float* W3  = smem;         // 576
    float* S9s = smem + 576;   // 5184
    float* W1s = smem + 5760;  // 576
    if (tid == 0) rowptr[N] = E;
    for (int e = tid; e < 576; e += 256) { W3[e] = Wc3[e]; W1s[e] = Wc1[e]; }
    __syncthreads();
    for (int bb = tid; bb < 576; bb += 256) {
      float acc[9];
#pragma unroll
      for (int a = 0; a < 9; ++a) acc[a] = 0.0f;
#pragma unroll 4
      for (int o = 0; o < 64; ++o) {
        float w2 = Wc2[o * 576 + bb];
#pragma unroll
        for (int a = 0; a < 9; ++a) acc[a] += W3[o * 9 + a] * w2;
      }
#pragma unroll
      for (int a = 0; a < 9; ++a) S9s[a * 576 + bb] = acc[a];
    }
    __syncthreads();
    for (int c = tid; c < 729; c += 256) {
      int kx0  = c % 3;
      int dl1e = (c / 3) % 3;
      int dl2e = (c / 9) % 3;
      int ky0  = (c / 27) % 3;
      int ky1  = (c / 81) % 3;
      int ky2  = c / 243;
      const float* s9 = &S9s[(ky2 * 3 + dl2e) * 576 + ky1 * 3 + dl1e];
      const float* w1 = &W1s[ky0 * 3 + kx0];
      float t = 0.0f;
#pragma unroll 8
      for (int i = 0; i < 64; ++i) t += s9[i * 9] * w1[i * 9];
      T729[c] = t;
    }
  } else if (s <= 5) {
    float* S2   = smem;          // 576
    float* W3b  = smem + 576;    // 576
    float* B2   = smem + 1152;   // 64
    float* part = smem + 1216;   // 256
    int var = s - 1;
    for (int e = tid; e < 576; e += 256) {
      int o = e / 9, r = e - o * 9;
      float t = 0.0f;
      for (int i = 0; i < 64; ++i) t += Wc2[o * 576 + i * 9 + r] * bc1[i];
      S2[e] = t;
      W3b[e] = Wc3[e];
    }
    if (tid < 64) B2[tid] = bc2[tid];
    __syncthreads();
    int u = tid & 63, oc = tid >> 6;
    float acc = 0.0f;
    for (int ky2 = 0; ky2 < 3; ++ky2) {
      int o2 = ky2 - 1;
      bool okA = (var == 0) ? (o2 >= 0) : (var == 4) ? (o2 <= 0) : true;
      if (!okA) continue;
      for (int dl2 = -1; dl2 <= 1; ++dl2) {
        int p = u + dl2; if ((unsigned)p >= 64u) continue;
        float sel[9];
#pragma unroll
        for (int ky1 = 0; ky1 < 3; ++ky1) {
          int o1 = ky1 - 1;
          bool mb = maskB(var, o2, o1);
#pragma unroll
          for (int dl1 = -1; dl1 <= 1; ++dl1) {
            int pq = p + dl1;
            sel[ky1 * 3 + dl1 + 1] = (mb && (unsigned)pq < 64u) ? 1.0f : 0.0f;
          }
        }
#pragma unroll 4
        for (int oo = 0; oo < 16; ++oo) {
          int o = oc * 16 + oo;
          float inner = B2[o];
#pragma unroll
          for (int r = 0; r < 9; ++r) inner += S2[o * 9 + r] * sel[r];
          acc += W3b[o * 9 + ky2 * 3 + (dl2 + 1)] * inner;
        }
      }
    }
    part[tid] = acc;
    __syncthreads();
    if (tid < 64) {
      beta5[var * 64 + tid] =
          bc3[0] + part[tid] + part[64 + tid] + part[128 + tid] + part[192 + tid];
    }
  } else {
    int idx = (s - 6) * 256 + tid;  // 0..37119
    if (idx < 16384) {
      int w = idx >> 7, u = idx & 127;
      Wt1[idx] = (u < 64) ? Wl1[u * 128 + w] : Wr1[(u - 64) * 128 + w];
    } else if (idx < 24576) {
      int t = idx - 16384;
      int w = t >> 7, u = t & 127;
      Wt2[t] = (u < 64) ? Wl2[u * 64 + w] : Wr2[(u - 64) * 64 + w];
    } else if (idx < 36864) {
      // S2 = P·P, S1 = Q·P + P·Q, S0 = Q·Q  with P=Wl2^T, Q=Wr2^T.
      int t2 = idx - 24576;
      int m = t2 >> 12, e = t2 & 4095;
      int i = e >> 6, j = e & 63;
      float acc = 0.0f;
#pragma unroll 4
      for (int k = 0; k < 64; ++k) {
        float wlj = Wl2[j * 64 + k], wrj = Wr2[j * 64 + k];
        float wli = Wl2[k * 64 + i], wri = Wr2[k * 64 + i];
        if (m == 0) acc += wli * wlj;
        else if (m == 1) acc += wri * wlj + wli * wrj;
        else acc += wri * wrj;
      }
      Sbuf[t2] = acc;
    } else if (idx < 36928) {
      // c5 = bl2^T (P + Q + I)
      int j = idx - 36864;
      float acc = bl2[j];
      for (int i = 0; i < 64; ++i)
        acc += bl2[i] * (Wl2[j * 64 + i] + Wr2[j * 64 + i]);
      c5[j] = acc;
    }
  }
}

// ============================ PHASE A2 =======================================
// blocks [0,157): partition (bases from bhist) | [157,219): M5T |
// [219,252): G-matrices | [252,1502): sage1 GEMM -> ybA(bf16) + zfA(fp32)
__global__ __launch_bounds__(256) void k_phaseA2(
    const float* __restrict__ X, const float* __restrict__ Wt1,
    unsigned short* __restrict__ ybA, float* __restrict__ zfA,
    const int* __restrict__ ei, const int* __restrict__ bhist,
    unsigned long long* __restrict__ ebuf,
    const float* __restrict__ T729, float* __restrict__ M5T,
    const float* __restrict__ Sbuf, const float* __restrict__ c5,
    const float* __restrict__ Wl3, const float* __restrict__ Wr3,
    const float* __restrict__ bl3, float* __restrict__ Gbuf,
    float* __restrict__ c32, int E, int N) {
  __shared__ float smem[2048];  // max branch: gemm Xs (16x128)
  int b = blockIdx.x, tid = threadIdx.x;
  if (b < 157) {
    int* lcnt  = (int*)smem;          // 79
    int* lbase = (int*)smem + 128;    // 79
    int* sscan = (int*)smem + 256;    // 128
    int st = probe_stride(ei);
    for (int i = tid; i < NBUK; i += 256) lcnt[i] = 0;
    int tot = 0, myoff = 0;
    if (tid < NBUK) {
      for (int v = 0; v < 157; ++v) {
        int h = bhist[v * NBUK + tid];
        tot += h;
        if (v < b) myoff += h;
      }
    }
    if (tid < 128) sscan[tid] = (tid < NBUK) ? tot : 0;
    __syncthreads();
    for (int off = 1; off < 128; off <<= 1) {
      int v = 0;
      if (tid < 128 && tid >= off) v = sscan[tid - off];
      __syncthreads();
      if (tid < 128) sscan[tid] += v;
      __syncthreads();
    }
    if (tid < NBUK) lbase[tid] = (sscan[tid] - tot) + myoff;
    __syncthreads();
    int e0 = b * 4096;
    int srcv[16], dstv[16], lrank[16], bk[16];
    int n = 0;
#pragma unroll
    for (int t = 0; t < 16; ++t) {
      int e = e0 + t * 256 + tid;
      if (e < E) {
        int sv = ei[(size_t)e * st];
        int d = ei[(size_t)(E + e) * st];
        int bb = d >> 8;
        srcv[n] = sv; dstv[n] = d; bk[n] = bb;
        lrank[n] = atomicAdd(&lcnt[bb], 1);
        ++n;
      }
    }
    for (int t = 0; t < n; ++t) {
      int pos = lbase[bk[t]] + lrank[t];
      ebuf[pos] = ((unsigned long long)(unsigned)dstv[t] << 32) | (unsigned)srcv[t];
    }
  } else if (b < 219) {
    float* Ts = smem;  // 729
    for (int e = tid; e < 729; e += 256) Ts[e] = T729[e];
    __syncthreads();
    int idx = (b - 157) * 256 + tid;
    if (idx >= 15680) return;
    int jw = idx % 7;
    int u  = (idx / 7) % 64;
    int d  = (idx / 448) % 7;
    int var = idx / 3136;
    int w = u + jw - 3;
    float acc = 0.0f;
    if (w >= 0 && w < 64) {
      for (int ky2 = 0; ky2 < 3; ++ky2) {
        int o2 = ky2 - 1;
        for (int ky1 = 0; ky1 < 3; ++ky1) {
          int o1 = ky1 - 1;
          if (!maskB(var, o2, o1)) continue;
          int o0 = (d - 3) - o2 - o1;
          if (o0 < -1 || o0 > 1) continue;
          int ky0 = o0 + 1;
          int cbase = ((ky2 * 3 + ky1) * 3 + ky0) * 27;
#pragma unroll
          for (int kx0 = 0; kx0 < 3; ++kx0) {
            int jq = jw - kx0;
            if ((unsigned)jq >= 5u) continue;
            int q = u + jq - 2;
            if ((unsigned)q >= 64u) continue;
#pragma unroll
            for (int dl2e = 0; dl2e < 3; ++dl2e) {
              int p = u + dl2e - 1;
              if ((unsigned)p >= 64u) continue;
              int dl1e = jq - dl2e;
              if ((unsigned)dl1e >= 3u) continue;
              acc += Ts[cbase + dl2e * 9 + dl1e * 3 + kx0];
            }
          }
        }
      }
    }
    if (d == 3 && jw == 3) acc += 1.0f;  // residual: out = conv(h) + h
    M5T[(var * 49 + d * 7 + jw) * 64 + u] = acc;
  } else if (b < 252) {
    int bb = b - 219;
    if (bb < 32) {
      int idx = bb * 256 + tid;  // [kblk][t][j]
      int kblk = idx >> 11;
      int rem = idx & 2047;
      int t = rem >> 5, j = rem & 31;
      const float* S2p = Sbuf;
      const float* S1p = Sbuf + 4096;
      const float* S0p = Sbuf + 8192;
      const float* pa = (kblk == 0) ? S2p : (kblk == 1) ? S1p : (kblk == 2) ? S0p : nullptr;
      const float* pb = (kblk == 1) ? S2p : (kblk == 2) ? S1p : (kblk == 3) ? S0p : nullptr;
      float acc = 0.0f;
#pragma unroll 4
      for (int k = 0; k < 64; ++k) {
        if (pa) acc += pa[t * 64 + k] * Wl3[j * 64 + k];
        if (pb) acc += pb[t * 64 + k] * Wr3[j * 64 + k];
      }
      Gbuf[idx] = acc;
    } else if (tid < 32) {
      float acc = bl3[tid];
      for (int k = 0; k < 64; ++k)
        acc += c5[k] * (Wl3[tid * 64 + k] + Wr3[tid * 64 + k]);
      c32[tid] = acc;
    }
  } else {
    // ---- sage1 GEMM: [yb|zf] = x · Wt1 ----
    constexpr int C = 128, K = 128, ROWS = 16, RPT = ROWS * C / 256;
    float* Xs = smem;
    int y0 = (b - 252) * ROWS;
    {
      const float4* src = (const float4*)(X + (size_t)y0 * K);
      float4* dst = (float4*)Xs;
#pragma unroll
      for (int v = 0; v < ROWS * K / 4 / 256; ++v)
        dst[v * 256 + tid] = src[v * 256 + tid];
    }
    __syncthreads();
    int u = tid % C;
    int rg = tid / C;
    float acc[RPT];
#pragma unroll
    for (int k = 0; k < RPT; ++k) acc[k] = 0.0f;
#pragma unroll 2
    for (int w0 = 0; w0 < K; w0 += 4) {
      float m0 = Wt1[(w0 + 0) * C + u];
      float m1 = Wt1[(w0 + 1) * C + u];
      float m2 = Wt1[(w0 + 2) * C + u];
      float m3 = Wt1[(w0 + 3) * C + u];
      const float* xs = &Xs[(rg * RPT) * K + w0];
#pragma unroll
      for (int k = 0; k < RPT; ++k) {
        float4 h = *(const float4*)(xs + k * K);
        acc[k] += m0 * h.x + m1 * h.y + m2 * h.z + m3 * h.w;
      }
    }
    if (u < 64) {
#pragma unroll
      for (int k = 0; k < RPT; ++k)
        ybA[(size_t)(y0 + rg * RPT + k) * 64 + u] = f2b(acc[k]);
    } else {
      int uz = u - 64;
#pragma unroll
      for (int k = 0; k < RPT; ++k)
        zfA[(size_t)(y0 + rg * RPT + k) * 64 + uz] = acc[k];
    }
  }
}

// ============================ PHASE A3 =======================================
// blocks [0,79): per-bucket counting sort | [79,112): Wg/bg
__global__ __launch_bounds__(256) void k_phaseA3(
    const unsigned long long* __restrict__ ebuf, const int* __restrict__ bhist,
    int* __restrict__ rowptr, float* __restrict__ invdeg,
    int* __restrict__ csr,
    const float* __restrict__ Gbuf, const float* __restrict__ W2,
    const float* __restrict__ b2, float* __restrict__ Wg,
    float* __restrict__ bg, int N) {
  __shared__ int smem[772];  // lcnt 256 | lcur 256 | wsum 4 | sscan 128 | tots 128
  int b = blockIdx.x, tid = threadIdx.x;
  if (b < NBUK) {
    int* lcnt  = smem;
    int* lcur  = smem + 256;
    int* wsum  = smem + 512;
    int* sscan = smem + 516;
    int* tots  = smem + 644;
    int tot = 0;
    if (tid < NBUK)
      for (int v = 0; v < 157; ++v) tot += bhist[v * NBUK + tid];
    if (tid < 128) {
      int tv = (tid < NBUK) ? tot : 0;
      tots[tid] = tv;
      sscan[tid] = tv;
    }
    __syncthreads();
    for (int off = 1; off < 128; off <<= 1) {
      int v = 0;
      if (tid < 128 && tid >= off) v = sscan[tid - off];
      __syncthreads();
      if (tid < 128) sscan[tid] += v;
      __syncthreads();
    }
    if (tid < 128) sscan[tid] -= tots[tid];  // exclusive prefix
    __syncthreads();
    int base = sscan[b];
    int n = tots[b];
    lcnt[tid] = 0;
    __syncthreads();
    for (int e = tid; e < n; e += 256) {
      int d = (int)(ebuf[base + e] >> 32);
      atomicAdd(&lcnt[d - (b << 8)], 1);
    }
    __syncthreads();
    int c = lcnt[tid];
    int lane = tid & 63, wid = tid >> 6;
    int s = c;
#pragma unroll
    for (int off = 1; off < 64; off <<= 1) {
      int v = __shfl_up(s, off, 64);
      if (lane >= off) s += v;
    }
    if (lane == 63) wsum[wid] = s;
    __syncthreads();
    int woff = 0;
    for (int w = 0; w < wid; ++w) woff += wsum[w];
    int pref = woff + s - c;  // exclusive
    int gnode = (b << 8) + tid;
    if (gnode < N) {
      rowptr[gnode] = base + pref;
      invdeg[gnode] = 1.0f / (float)(c < 1 ? 1 : c);
    }
    lcur[tid] = pref;
    __syncthreads();
    for (int e = tid; e < n; e += 256) {
      unsigned long long pk = ebuf[base + e];
      int d = (int)(pk >> 32);
      int pos = atomicAdd(&lcur[d - (b << 8)], 1);
      csr[base + pos] = (int)(unsigned)pk;
    }
  } else {
    int bb = b - NBUK;
    if (bb < 32) {
      int idx = bb * 256 + tid;  // Wg[w*128+u]
      int w = idx >> 7, u = idx & 127;
      int kblk = u >> 5, j = u & 31;
      const float* gp = Gbuf + kblk * 2048 + j;
      float acc = 0.0f;
#pragma unroll 4
      for (int t = 0; t < 64; ++t) acc += W2[t * 64 + w] * gp[t * 32];
      Wg[idx] = acc;
    } else if (tid < 128) {
      int kblk = tid >> 5, j = tid & 31;
      const float* gp = Gbuf + kblk * 2048 + j;
      float acc = 0.0f;
      for (int t = 0; t < 64; ++t) acc += b2[t] * gp[t * 32];
      bg[tid] = acc;
    }
  }
}

// ---------- fused mean-aggregation (bf16 gather) + GEMM ---------------------
// gather yb (bf16 N×64 = 2 lines/edge vs 4 for fp32) + root zf (fp32) ->
// h fp32 in LDS -> h·Wt (64×128) -> ybo (bf16) + zfo (fp32)
__global__ __launch_bounds__(256) void k_fusedb(
    const unsigned short* __restrict__ yb, const float* __restrict__ zf,
    const int* __restrict__ csr, const int* __restrict__ rowptr,
    const float* __restrict__ invdeg, const float* __restrict__ bl,
    const float* __restrict__ Wt, unsigned short* __restrict__ ybo,
    float* __restrict__ zfo, int N) {
  constexpr int CAP = 64;
  __shared__ int idxs[16 * CAP];
  __shared__ float htile[16 * 64];
  int tid = threadIdx.x;
  int w = tid >> 6, lane = tid & 63;
  int base = blockIdx.x * 16;
  int beg_r[4], m_r[4], end_r[4];
#pragma unroll
  for (int rr = 0; rr < 4; ++rr) {
    int node = base + w * 4 + rr;
    int beg = rowptr[node], end = rowptr[node + 1];
    beg_r[rr] = beg; end_r[rr] = end;
    int cnt = end - beg;
    int m = cnt < CAP ? cnt : CAP;
    m_r[rr] = m;
    int* my = &idxs[(w * 4 + rr) * CAP];
    for (int k = lane; k < m; k += 64) my[k] = csr[beg + k];
  }
  __syncthreads();
  int g = lane >> 3, f = lane & 7;      // 8 neighbor-groups × 8 uint4-lanes
  const uint4* yb4 = (const uint4*)yb;  // row = 8 uint4 (64 bf16 = 128 B)
#pragma unroll
  for (int rr = 0; rr < 4; ++rr) {
    int node = base + w * 4 + rr;
    const int* my = &idxs[(w * 4 + rr) * CAP];
    int m = m_r[rr];
    float a[8] = {0, 0, 0, 0, 0, 0, 0, 0};
    float bacc[8] = {0, 0, 0, 0, 0, 0, 0, 0};
    int j = g;
    for (; j + 8 < m; j += 16) {
      int s0 = my[j], s1 = my[j + 8];
      uint4 v0 = yb4[(size_t)s0 * 8 + f];
      uint4 v1 = yb4[(size_t)s1 * 8 + f];
      bacc8(a, v0);
      bacc8(bacc, v1);
    }
    for (; j < m; j += 8) bacc8(a, yb4[(size_t)my[j] * 8 + f]);
    for (int jj = beg_r[rr] + CAP + g; jj < end_r[rr]; jj += 8)
      bacc8(a, yb4[(size_t)csr[jj] * 8 + f]);
#pragma unroll
    for (int i = 0; i < 8; ++i) a[i] += bacc[i];
#pragma unroll
    for (int mm = 8; mm < 64; mm <<= 1)
#pragma unroll
      for (int i = 0; i < 8; ++i) a[i] += __shfl_xor(a[i], mm, 64);
    if (g == 0) {
      float id = invdeg[node];
      const float* zr = zf + (size_t)node * 64 + f * 8;
      const float* bp = bl + f * 8;
      float* ht = &htile[(w * 4 + rr) * 64 + f * 8];
#pragma unroll
      for (int i = 0; i < 8; ++i) ht[i] = a[i] * id + bp[i] + zr[i];
    }
  }
  __syncthreads();
  int u = tid & 127, rg = tid >> 7;
  float acc[8];
#pragma unroll
  for (int k = 0; k < 8; ++k) acc[k] = 0.0f;
#pragma unroll 2
  for (int w0 = 0; w0 < 64; w0 += 4) {
    float m0 = Wt[(w0 + 0) * 128 + u];
    float m1 = Wt[(w0 + 1) * 128 + u];
    float m2 = Wt[(w0 + 2) * 128 + u];
    float m3 = Wt[(w0 + 3) * 128 + u];
    const float* xs = &htile[(rg * 8) * 64 + w0];
#pragma unroll
    for (int k = 0; k < 8; ++k) {
      float4 h4 = *(const float4*)(xs + k * 64);
      acc[k] += m0 * h4.x + m1 * h4.y + m2 * h4.z + m3 * h4.w;
    }
  }
  if (u < 64) {
#pragma unroll
    for (int k = 0; k < 8; ++k)
      ybo[(size_t)(base + rg * 8 + k) * 64 + u] = f2b(acc[k]);
  } else {
    int uz = u - 64;
#pragma unroll
    for (int k = 0; k < 8; ++k)
      zfo[(size_t)(base + rg * 8 + k) * 64 + uz] = acc[k];
  }
}

// ---------- agg3: bf16 gather -> hA fp32 (conv input keeps full precision) --
__global__ __launch_bounds__(256) void k_aggb64(
    const unsigned short* __restrict__ yb, const float* __restrict__ zf,
    const int* __restrict__ csr, const int* __restrict__ rowptr,
    const float* __restrict__ invdeg, const float* __restrict__ bl,
    float* __restrict__ out, int N) {
  constexpr int CAP = 256;
  __shared__ int idxs[4 * CAP];
  int wid = threadIdx.x >> 6, lane = threadIdx.x & 63;
  int node = blockIdx.x * 4 + wid;
  int beg = rowptr[node], end = rowptr[node + 1];
  int cnt = end - beg;
  int m = cnt < CAP ? cnt : CAP;
  int* my = &idxs[wid * CAP];
  for (int k = lane; k < m; k += 64) my[k] = csr[beg + k];
  __syncthreads();
  int g = lane >> 3, f = lane & 7;
  const uint4* yb4 = (const uint4*)yb;
  float a[8] = {0, 0, 0, 0, 0, 0, 0, 0};
  float bacc[8] = {0, 0, 0, 0, 0, 0, 0, 0};
  int j = g;
  for (; j + 8 < m; j += 16) {
    int s0 = my[j], s1 = my[j + 8];
    uint4 v0 = yb4[(size_t)s0 * 8 + f];
    uint4 v1 = yb4[(size_t)s1 * 8 + f];
    bacc8(a, v0);
    bacc8(bacc, v1);
  }
  for (; j < m; j += 8) bacc8(a, yb4[(size_t)my[j] * 8 + f]);
  for (int jj = beg + CAP + g; jj < end; jj += 8)
    bacc8(a, yb4[(size_t)csr[jj] * 8 + f]);
#pragma unroll
  for (int i = 0; i < 8; ++i) a[i] += bacc[i];
#pragma unroll
  for (int mm = 8; mm < 64; mm <<= 1)
#pragma unroll
    for (int i = 0; i < 8; ++i) a[i] += __shfl_xor(a[i], mm, 64);
  if (g == 0) {
    float id = invdeg[node];
    const float* zr = zf + (size_t)node * 64 + f * 8;
    const float* bp = bl + f * 8;
    float o[8];
#pragma unroll
    for (int i = 0; i < 8; ++i) o[i] = a[i] * id + bp[i] + zr[i];
    float* op = out + (size_t)node * 64 + f * 8;
    ((float4*)op)[0] = make_float4(o[0], o[1], o[2], o[3]);
    ((float4*)op)[1] = make_float4(o[4], o[5], o[6], o[7]);
  }
}

// ---------- conv-composite apply + collapse; output wbuf bf16 ---------------
__global__ __launch_bounds__(256) void k_applyb(
    const float* __restrict__ h, const float* __restrict__ M5T,
    const float* __restrict__ beta5, const float* __restrict__ Wg,
    const float* __restrict__ bg, unsigned short* __restrict__ wout, int N) {
  __shared__ float hs[22 * 70];
  __shared__ float htile[16 * 64];
  int tid = threadIdx.x;
  int bstart = blockIdx.x * 16;
  for (int idx = tid; idx < 22 * 70; idx += 256) {
    int row = idx / 70, col = idx - row * 70;
    int y = bstart - 3 + row;
    int ww = col - 3;
    float v = 0.0f;
    if ((unsigned)y < (unsigned)N && (unsigned)ww < 64u)
      v = h[(size_t)y * 64 + ww];
    hs[idx] = v;
  }
  __syncthreads();
  int u = tid & 63, g = tid >> 6;
  int lr0 = g * 4;
  int gstart = bstart + lr0;
  const float* basep = &hs[lr0 * 70 + u];
  bool interior = (gstart >= 2) && (gstart + 3 <= N - 3);
  if (interior) {
    float c[49];
#pragma unroll
    for (int t = 0; t < 49; ++t) c[t] = M5T[(2 * 49 + t) * 64 + u];
    float bet = beta5[2 * 64 + u];
    float acc[4];
#pragma unroll
    for (int k = 0; k < 4; ++k) acc[k] = bet;
#pragma unroll
    for (int rr = 0; rr < 10; ++rr) {
      float t7[7];
#pragma unroll
      for (int jw = 0; jw < 7; ++jw) t7[jw] = basep[rr * 70 + jw];
#pragma unroll
      for (int d = 0; d < 7; ++d) {
        int k = rr - d;
        if (k >= 0 && k < 4) {
#pragma unroll
          for (int jw = 0; jw < 7; ++jw) acc[k] += c[d * 7 + jw] * t7[jw];
        }
      }
    }
#pragma unroll
    for (int k = 0; k < 4; ++k) htile[(lr0 + k) * 64 + u] = acc[k];
  } else {
    for (int k = 0; k < 4; ++k) {
      int y = gstart + k;
      int var = (y == 0) ? 0 : (y == 1) ? 1 : (y == N - 2) ? 3 : (y == N - 1) ? 4 : 2;
      float acc = beta5[var * 64 + u];
      for (int d = 0; d < 7; ++d)
        for (int jw = 0; jw < 7; ++jw)
          acc += M5T[(var * 49 + d * 7 + jw) * 64 + u] * basep[(k + d) * 70 + jw];
      htile[(lr0 + k) * 64 + u] = acc;
    }
  }
  __syncthreads();
  int u2 = tid % 128, rg = tid / 128;
  float acc2[8];
  float bv = bg[u2];
#pragma unroll
  for (int k = 0; k < 8; ++k) acc2[k] = bv;
#pragma unroll 2
  for (int w0 = 0; w0 < 64; w0 += 4) {
    float m0 = Wg[(w0 + 0) * 128 + u2];
    float m1 = Wg[(w0 + 1) * 128 + u2];
    float m2 = Wg[(w0 + 2) * 128 + u2];
    float m3 = Wg[(w0 + 3) * 128 + u2];
    const float* xs = &htile[(rg * 8) * 64 + w0];
#pragma unroll
    for (int k = 0; k < 8; ++k) {
      float4 h4 = *(const float4*)(xs + k * 64);
      acc2[k] += m0 * h4.x + m1 * h4.y + m2 * h4.z + m3 * h4.w;
    }
  }
  int kb = u2 >> 5, jj = u2 & 31;
#pragma unroll
  for (int k = 0; k < 8; ++k) {
    int node = bstart + rg * 8 + k;
    wout[((size_t)kb * N + node) * 32 + jj] = f2b(acc2[k]);
  }
}

// ---- 32-wide bf16 mean aggregation + add: out = (A src)·invdeg + add [+cvec]
// src/add bf16 (row = 64 B = 1 line/edge); out bf16 (outb) or fp32 (outf).
__global__ __launch_bounds__(256) void k_agg32b(
    const unsigned short* __restrict__ src, const int* __restrict__ csr,
    const int* __restrict__ rowptr, const float* __restrict__ invdeg,
    const unsigned short* __restrict__ addb, const float* __restrict__ cvec,
    unsigned short* __restrict__ outb, float* __restrict__ outf, int N) {
  constexpr int CAP = 256;
  __shared__ int idxs[4 * CAP];
  int wid = threadIdx.x >> 6, lane = threadIdx.x & 63;
  int node = blockIdx.x * 4 + wid;
  int beg = rowptr[node], end = rowptr[node + 1];
  int cnt = end - beg;
  int m = cnt < CAP ? cnt : CAP;
  int* my = &idxs[wid * CAP];
  for (int k = lane; k < m; k += 64) my[k] = csr[beg + k];
  __syncthreads();
  int g = lane >> 2, f = lane & 3;      // 16 neighbor-groups × 4 uint4-lanes
  const uint4* sr4 = (const uint4*)src; // row = 4 uint4 (32 bf16 = 64 B)
  float a[8] = {0, 0, 0, 0, 0, 0, 0, 0};
  float bacc[8] = {0, 0, 0, 0, 0, 0, 0, 0};
  int j = g;
  for (; j + 16 < m; j += 32) {
    int s0 = my[j], s1 = my[j + 16];
    uint4 v0 = sr4[(size_t)s0 * 4 + f];
    uint4 v1 = sr4[(size_t)s1 * 4 + f];
    bacc8(a, v0);
    bacc8(bacc, v1);
  }
  for (; j < m; j += 16) bacc8(a, sr4[(size_t)my[j] * 4 + f]);
  for (int jj = beg + CAP + g; jj < end; jj += 16)
    bacc8(a, sr4[(size_t)csr[jj] * 4 + f]);
#pragma unroll
  for (int i = 0; i < 8; ++i) a[i] += bacc[i];
#pragma unroll
  for (int mm = 4; mm < 64; mm <<= 1)
#pragma unroll
    for (int i = 0; i < 8; ++i) a[i] += __shfl_xor(a[i], mm, 64);
  if (g == 0) {
    float id = invdeg[node];
    float ad[8];
    bget8(ad, ((const uint4*)addb)[(size_t)node * 4 + f]);
    float o[8];
#pragma unroll
    for (int i = 0; i < 8; ++i) o[i] = a[i] * id + ad[i];
    if (cvec != nullptr) {
#pragma unroll
      for (int i = 0; i < 8; ++i) o[i] += cvec[f * 8 + i];
    }
    if (outb != nullptr) {
      uint4 pv;
      pv.x = pk2(o[0], o[1]); pv.y = pk2(o[2], o[3]);
      pv.z = pk2(o[4], o[5]); pv.w = pk2(o[6], o[7]);
      ((uint4*)outb)[(size_t)node * 4 + f] = pv;
    } else {
      float* op = outf + (size_t)node * 32 + f * 8;
      ((float4*)op)[0] = make_float4(o[0], o[1], o[2], o[3]);
      ((float4*)op)[1] = make_float4(o[4], o[5], o[6], o[7]);
    }
  }
}

// ------------------------------- launcher -----------------------------------
extern "C" void kernel_launch(void* const* d_in, const int* in_sizes, int n_in,
                              void* d_out, int out_size, void* d_ws, size_t ws_size,
                              hipStream_t stream) {
  const int N = NN, E = NE;
  const float* x   = (const float*)d_in[0];
  const int*   ei  = (const int*)d_in[1];
  const float* Wl1 = (const float*)d_in[2];
  const float* bl1 = (const float*)d_in[3];
  const float* Wr1 = (const float*)d_in[4];
  const float* Wl2 = (const float*)d_in[5];
  const float* bl2 = (const float*)d_in[6];
  const float* Wr2 = (const float*)d_in[7];
  const float* Wl3 = (const float*)d_in[8];
  const float* bl3 = (const float*)d_in[9];
  const float* Wr3 = (const float*)d_in[10];
  const float* Wc1 = (const float*)d_in[11];
  const float* bc1 = (const float*)d_in[12];
  const float* Wc2 = (const float*)d_in[13];
  const float* bc2 = (const float*)d_in[14];
  const float* Wc3 = (const float*)d_in[15];
  const float* bc3 = (const float*)d_in[16];
  const float* W2  = (const float*)d_in[17];
  const float* b2  = (const float*)d_in[18];

  char* ws = (char*)d_ws;
  size_t off = 0;
  auto alloc = [&](size_t bytes) -> void* {
    off = (off + 255) & ~(size_t)255;
    void* p = ws + off;
    off += bytes;
    return p;
  };
  int*   rowptr  = (int*)alloc((size_t)(N + 1) * 4);
  float* invdeg  = (float*)alloc((size_t)N * 4);
  int*   csr     = (int*)alloc((size_t)E * 4);
  unsigned long long* ebuf = (unsigned long long*)alloc((size_t)E * 8);
  int*   bhist   = (int*)alloc(157 * NBUK * 4);  // per-block hist rows (no init)
  float* Wt1     = (float*)alloc(128 * 128 * 4);
  float* Wt2     = (float*)alloc(64 * 128 * 4);
  float* T729    = (float*)alloc(729 * 4);
  float* M5T     = (float*)alloc(15680 * 4);
  float* beta5   = (float*)alloc(320 * 4);
  float* Sbuf    = (float*)alloc(12288 * 4);
  float* c5      = (float*)alloc(64 * 4);
  float* Gbuf    = (float*)alloc(8192 * 4);
  float* Wg      = (float*)alloc(8192 * 4);
  float* bg      = (float*)alloc(128 * 4);
  float* c32     = (float*)alloc(32 * 4);
  unsigned short* ybA = (unsigned short*)alloc((size_t)N * 64 * 2);
  unsigned short* ybB = (unsigned short*)alloc((size_t)N * 64 * 2);
  float* zfA     = (float*)alloc((size_t)N * 64 * 4);
  float* zfB     = (float*)alloc((size_t)N * 64 * 4);
  float* hA      = (float*)alloc((size_t)N * 64 * 4);
  unsigned short* wb  = (unsigned short*)alloc((size_t)4 * N * 32 * 2);
  unsigned short* s1b = (unsigned short*)alloc((size_t)N * 32 * 2);
  unsigned short* s2b = (unsigned short*)alloc((size_t)N * 32 * 2);
  (void)ws_size; (void)in_sizes; (void)n_in; (void)out_size;

  const int gG = N / 16;  // 1250
  const int gA = N / 4;   // 5000

  // A1: setup(151) || hist(157)
  k_phaseA1<<<308, 256, 0, stream>>>(ei, bhist, Wc1, Wc2, Wc3, bc1, bc2, bc3,
                                     Wl1, Wr1, Wl2, Wr2, bl2,
                                     T729, beta5, Wt1, Wt2, Sbuf, c5,
                                     rowptr, E, N);
  // A2: part(157) || m5(62) || setupG(33) || sage1-GEMM(1250)
  k_phaseA2<<<1502, 256, 0, stream>>>(x, Wt1, ybA, zfA, ei, bhist, ebuf,
                                      T729, M5T, Sbuf, c5, Wl3, Wr3, bl3,
                                      Gbuf, c32, E, N);
  // A3: sortb(79) || setupWg(33)
  k_phaseA3<<<112, 256, 0, stream>>>(ebuf, bhist, rowptr, invdeg, csr,
                                     Gbuf, W2, b2, Wg, bg, N);

  // [agg1 + sage2-transform]
  k_fusedb<<<gG, 256, 0, stream>>>(ybA, zfA, csr, rowptr, invdeg, bl1, Wt2,
                                   ybB, zfB, N);
  // [agg2 + sage3-transform]
  k_fusedb<<<gG, 256, 0, stream>>>(ybB, zfB, csr, rowptr, invdeg, bl2, Wt2,
                                   ybA, zfA, N);
  // agg3 -> hA (conv input, fp32)
  k_aggb64<<<gA, 256, 0, stream>>>(ybA, zfA, csr, rowptr, invdeg, bl2, hA, N);
  // [conv-composite + residual + linear2 + sage4-6 collapse] -> w3|w2|w1|w0
  k_applyb<<<gG, 256, 0, stream>>>(hA, M5T, beta5, Wg, bg, wb, N);
  // collapsed sage4-6: out = A(A(A w3 + w2) + w1) + w0 + c32
  const unsigned short* w3  = wb;
  const unsigned short* w2p = wb + (size_t)N * 32;
  const unsigned short* w1p = wb + (size_t)2 * N * 32;
  const unsigned short* w0p = wb + (size_t)3 * N * 32;
  k_agg32b<<<gA, 256, 0, stream>>>(w3, csr, rowptr, invdeg, w2p, nullptr,
                                   s1b, nullptr, N);
  k_agg32b<<<gA, 256, 0, stream>>>(s1b, csr, rowptr, invdeg, w1p, nullptr,
                                   s2b, nullptr, N);
  k_agg32b<<<gA, 256, 0, stream>>>(s2b, csr, rowptr, invdeg, w0p, c32,
                                   nullptr, (float*)d_out, N);
}